// Round 7
// baseline (2170.689 us; speedup 1.0000x reference)
//
#include <hip/hip_runtime.h>
#include <hip/hip_bf16.h>

#define EMB_D 100
#define WPK 52            // padded u32-pairs per emb row (104 f16)
#define HID 64
#define G4 256
#define BATCH 128
#define SEQ 1024
#define NB 16             // batch columns per lstm block
#define NBLK 8
#define TCHK 16           // timesteps per xw0 block
#define HP 68             // padded h row length (f16 elems) to break banks
#define TILE 4096         // u16 per xw timestep tile (G4*NB)

typedef _Float16 f16x2 __attribute__((ext_vector_type(2)));
typedef _Float16 f16x4 __attribute__((ext_vector_type(4)));
typedef float    f32x4 __attribute__((ext_vector_type(4)));
typedef unsigned short u16;
typedef unsigned int   u32;

__device__ __forceinline__ float sigf(float x) { return 1.0f / (1.0f + __expf(-x)); }
__device__ __forceinline__ float tanh_fast(float x) {
  float t = __expf(-2.0f * fabsf(x));
  float r = (1.0f - t) / (1.0f + t);
  return copysignf(r, x);
}
__device__ __forceinline__ float dot2(u32 h, u32 w, float acc) {
  return __builtin_amdgcn_fdot2(__builtin_bit_cast(f16x2, h),
                                __builtin_bit_cast(f16x2, w), acc, false);
}
__device__ __forceinline__ u32 packh2(float lo, float hi) {
  u16 a = __builtin_bit_cast(u16, (_Float16)lo);
  u16 b = __builtin_bit_cast(u16, (_Float16)hi);
  return (u32)a | ((u32)b << 16);
}
__device__ __forceinline__ f32x4 mfma16(uint2 a, uint2 b, f32x4 c) {
  return __builtin_amdgcn_mfma_f32_16x16x16f16(
      __builtin_bit_cast(f16x4, a), __builtin_bit_cast(f16x4, b), c, 0, 0, 0);
}

// ---------------- prep: biases + f16-packed weights ----------------
__global__ void prep_kernel(const float* __restrict__ Wih0, const float* __restrict__ Whh0,
                            const float* __restrict__ Wih1, const float* __restrict__ Whh1,
                            const float* __restrict__ bih0, const float* __restrict__ bhh0,
                            const float* __restrict__ bih1, const float* __restrict__ bhh1,
                            u32* __restrict__ Wih0h, float* __restrict__ b0c,
                            float* __restrict__ b1c, u32* __restrict__ Whh0h,
                            u32* __restrict__ Wih1h, u32* __restrict__ Whh1h) {
  int g = threadIdx.x;
  b0c[g] = bih0[g] + bhh0[g];
  b1c[g] = bih1[g] + bhh1[g];
  for (int d = 0; d < 50; ++d)
    Wih0h[g * WPK + d] = packh2(Wih0[g * EMB_D + 2 * d], Wih0[g * EMB_D + 2 * d + 1]);
  Wih0h[g * WPK + 50] = 0;
  Wih0h[g * WPK + 51] = 0;
  for (int d = 0; d < 32; ++d) {
    Whh0h[g * 32 + d] = packh2(Whh0[g * HID + 2 * d], Whh0[g * HID + 2 * d + 1]);
    Wih1h[g * 32 + d] = packh2(Wih1[g * HID + 2 * d], Wih1[g * HID + 2 * d + 1]);
    Whh1h[g * 32 + d] = packh2(Whh1[g * HID + 2 * d], Whh1[g * HID + 2 * d + 1]);
  }
}

// ---------------- xw0: f16 dot2 GEMV, tiled [bb][t][gate][n] output ----------------
__global__ __launch_bounds__(256, 2) void xw0_kernel(
    const int* __restrict__ x, const float* __restrict__ emb,
    const u32* __restrict__ Wih0h, const float* __restrict__ b0c,
    u16* __restrict__ xwT) {
  __shared__ int sidx[256];
  __shared__ u16 erow[256][2 * WPK];  // 104 u16 per row (208B, 16B-aligned)
  const int tid = threadIdx.x;
  const int bb = blockIdx.x & 7;
  const int tc = blockIdx.x >> 3;
  const int t0 = tc * TCHK;
  const int b0 = bb * NB;

  {
    int nn = tid >> 4, tt = tid & 15;
    sidx[tid] = x[(size_t)(b0 + nn) * SEQ + t0 + tt];
  }
  __syncthreads();
  for (int i = tid; i < 256 * EMB_D; i += 256) {
    int row = i / EMB_D;
    int d = i - row * EMB_D;
    erow[row][d] = __builtin_bit_cast(u16, (_Float16)emb[(size_t)sidx[row] * EMB_D + d]);
  }
  for (int i = tid; i < 256 * 4; i += 256)
    erow[i >> 2][EMB_D + (i & 3)] = 0;

  u32 wreg[WPK];
  #pragma unroll
  for (int d = 0; d < WPK; ++d) wreg[d] = Wih0h[tid * WPK + d];
  float bb0 = b0c[tid];
  __syncthreads();

  for (int tok = 0; tok < 256; ++tok) {
    const uint4* ep = (const uint4*)erow[tok];
    float a0 = bb0, a1 = 0.f, a2 = 0.f, a3 = 0.f;
    #pragma unroll
    for (int c = 0; c < 13; ++c) {
      uint4 hv = ep[c];
      a0 = dot2(hv.x, wreg[4 * c],     a0);
      a1 = dot2(hv.y, wreg[4 * c + 1], a1);
      a2 = dot2(hv.z, wreg[4 * c + 2], a2);
      a3 = dot2(hv.w, wreg[4 * c + 3], a3);
    }
    float s = (a0 + a1) + (a2 + a3);
    int nn = tok >> 4, tt = tok & 15;
    xwT[(((size_t)bb * SEQ + t0 + tt) * G4 + tid) * NB + nn] =
        __builtin_bit_cast(u16, (_Float16)s);
  }
}

// ---------------- fused MFMA recurrence: 8 blocks x 16 batch cols ----------------
// 8 waves: w<4 -> layer0 (wave om owns M-tiles {om,om+4,om+8,om+12}), w>=4 -> layer1.
// v_mfma_f32_16x16x16f16 layouts: A[m=l&15][k=4q+j], B[k=4q+j][n=l&15],
// D[row=4q+r][col=l&15]. Element e=16*om+4q+r has (i,f,g,o) at acc tiles j=0..3,
// same lane, same reg r -> lane-local activation, no shuffles.
__global__ __launch_bounds__(512, 2) void lstm_fused_kernel(
    const u16* __restrict__ xwT, const u32* __restrict__ Whh0h,
    const u32* __restrict__ Wih1h, const u32* __restrict__ Whh1h,
    const float* __restrict__ b1c, const float* __restrict__ W1,
    const float* __restrict__ clsb1, const float* __restrict__ W2,
    const float* __restrict__ clsb2, float* __restrict__ out) {
  const int tid = threadIdx.x;
  const int l = tid & 63;
  const int w = tid >> 6;
  const bool isL1 = (w >= 4);
  const int om = w & 3;
  const int q = l >> 4;
  const int n = l & 15;
  const int e0 = 16 * om + 4 * q;

  __shared__ u16 xwb[3][TILE];              // triple-buffered xw tiles (8KB each)
  __shared__ _Float16 h0s[2][NB][HP];       // [buf][n][k], padded to 68
  __shared__ _Float16 h1s[2][NB][HP];
  __shared__ float hf[NB][HP];              // final h1 (f32) for classifier

  for (int i = tid; i < 2 * NB * HP; i += 512) {
    ((u16*)h0s)[i] = 0;
    ((u16*)h1s)[i] = 0;
  }

  // A fragments: aW = Whh0 (L0) / Wih1 (L1); aV = Whh1 (L1 only)
  uint2 aW[4][4], aV[4][4];
  #pragma unroll
  for (int j = 0; j < 4; ++j) {
    int rr = 16 * (om + 4 * j) + n;         // A row index for this lane
    #pragma unroll
    for (int kt = 0; kt < 4; ++kt) {
      const u32* srcW = (isL1 ? Wih1h : Whh0h) + rr * 32 + 8 * kt + 2 * q;
      aW[j][kt] = *(const uint2*)srcW;
      if (isL1) aV[j][kt] = *(const uint2*)(Whh1h + rr * 32 + 8 * kt + 2 * q);
      else      aV[j][kt] = uint2{0u, 0u};
    }
  }
  #pragma unroll
  for (int j = 0; j < 4; ++j)
    #pragma unroll
    for (int kt = 0; kt < 4; ++kt)
      asm volatile("" : "+v"(aW[j][kt].x), "+v"(aW[j][kt].y),
                        "+v"(aV[j][kt].x), "+v"(aV[j][kt].y));

  f32x4 bias[4];
  #pragma unroll
  for (int j = 0; j < 4; ++j) {
    if (isL1) bias[j] = *(const f32x4*)(b1c + 64 * j + e0);
    else      bias[j] = f32x4{0.f, 0.f, 0.f, 0.f};
  }

  // xw pipeline: tiles 0,1 -> LDS now; tiles 2,3 -> regs (distance-2 stage)
  const u16* xsrc = xwT + (size_t)blockIdx.x * SEQ * TILE;
  const int toff = tid * 8;
  uint4 T0 = *(const uint4*)(xsrc + 0 * TILE + toff);
  uint4 T1 = *(const uint4*)(xsrc + 1 * TILE + toff);
  uint4 RA = *(const uint4*)(xsrc + 2 * TILE + toff);
  uint4 RB = *(const uint4*)(xsrc + 3 * TILE + toff);
  *(uint4*)&xwb[0][toff] = T0;
  *(uint4*)&xwb[1][toff] = T1;
  float creg0 = 0.f, creg1 = 0.f, creg2 = 0.f, creg3 = 0.f;
  __syncthreads();   // prologue only: drains everything, all buffers visible

  for (int t = 0; t < SEQ; ++t) {
    const int rbuf = t % 3;
    const int rh = (t + 1) & 1;   // read h buffer
    const int wh = t & 1;         // write h buffer

    // stage tile t+2 into LDS (compiler inserts counted vmcnt before this
    // ds_write); issue load of tile t+4 (rides across the raw barrier)
    *(uint4*)&xwb[(t + 2) % 3][toff] = RA;
    RA = RB;
    {
      int tl = (t + 4 < SEQ) ? (t + 4) : (SEQ - 1);
      RB = *(const uint4*)(xsrc + (size_t)tl * TILE + toff);
    }

    // B fragments from h state
    uint2 b0r[4], b1r[4];
    {
      const _Float16* hb = &h0s[rh][n][4 * q];
      #pragma unroll
      for (int kt = 0; kt < 4; ++kt) b0r[kt] = *(const uint2*)(hb + 16 * kt);
    }
    if (isL1) {
      const _Float16* hb = &h1s[rh][n][4 * q];
      #pragma unroll
      for (int kt = 0; kt < 4; ++kt) b1r[kt] = *(const uint2*)(hb + 16 * kt);
    } else {
      #pragma unroll
      for (int kt = 0; kt < 4; ++kt) b1r[kt] = uint2{0u, 0u};
    }

    // xw gate inputs (L0 only): 16 u16 LDS reads, issued early
    u16 xv[16];
    if (!isL1) {
      const u16* xp = xwb[rbuf];
      #pragma unroll
      for (int j = 0; j < 4; ++j)
        #pragma unroll
        for (int r = 0; r < 4; ++r)
          xv[4 * j + r] = xp[(e0 + 64 * j + r) * NB + n];
    }

    // MFMA: acc tile j = gate-quarter j
    f32x4 accP[4];
    #pragma unroll
    for (int j = 0; j < 4; ++j) accP[j] = bias[j];
    #pragma unroll
    for (int kt = 0; kt < 4; ++kt)
      #pragma unroll
      for (int j = 0; j < 4; ++j)
        accP[j] = mfma16(aW[j][kt], b0r[kt], accP[j]);
    if (isL1) {
      f32x4 accQ[4];
      #pragma unroll
      for (int j = 0; j < 4; ++j) accQ[j] = f32x4{0.f, 0.f, 0.f, 0.f};
      #pragma unroll
      for (int kt = 0; kt < 4; ++kt)
        #pragma unroll
        for (int j = 0; j < 4; ++j)
          accQ[j] = mfma16(aV[j][kt], b1r[kt], accQ[j]);
      #pragma unroll
      for (int j = 0; j < 4; ++j) accP[j] += accQ[j];
    }

    const bool doact = (!isL1) || (t > 0);
    if (doact) {
      float gv[4][4];
      #pragma unroll
      for (int j = 0; j < 4; ++j)
        #pragma unroll
        for (int r = 0; r < 4; ++r) {
          float v = accP[j][r];
          if (!isL1) v += (float)__builtin_bit_cast(_Float16, xv[4 * j + r]);
          gv[j][r] = v;
        }
      float hv0, hv1, hv2, hv3;
      creg0 = sigf(gv[1][0]) * creg0 + sigf(gv[0][0]) * tanh_fast(gv[2][0]);
      hv0 = sigf(gv[3][0]) * tanh_fast(creg0);
      creg1 = sigf(gv[1][1]) * creg1 + sigf(gv[0][1]) * tanh_fast(gv[2][1]);
      hv1 = sigf(gv[3][1]) * tanh_fast(creg1);
      creg2 = sigf(gv[1][2]) * creg2 + sigf(gv[0][2]) * tanh_fast(gv[2][2]);
      hv2 = sigf(gv[3][2]) * tanh_fast(creg2);
      creg3 = sigf(gv[1][3]) * creg3 + sigf(gv[0][3]) * tanh_fast(gv[2][3]);
      hv3 = sigf(gv[3][3]) * tanh_fast(creg3);
      uint2 hw;
      hw.x = packh2(hv0, hv1);
      hw.y = packh2(hv2, hv3);
      _Float16* dst = isL1 ? &h1s[wh][n][e0] : &h0s[wh][n][e0];
      *(uint2*)dst = hw;
    }

    asm volatile("s_waitcnt lgkmcnt(0)" ::: "memory");
    __builtin_amdgcn_s_barrier();
    asm volatile("" ::: "memory");
  }

  // final layer-1 step: h1[1023] from h0s[1] (=h0[1023]) and h1s[1] (=h1[1022])
  if (isL1) {
    uint2 b0r[4], b1r[4];
    const _Float16* hb0 = &h0s[1][n][4 * q];
    const _Float16* hb1 = &h1s[1][n][4 * q];
    #pragma unroll
    for (int kt = 0; kt < 4; ++kt) {
      b0r[kt] = *(const uint2*)(hb0 + 16 * kt);
      b1r[kt] = *(const uint2*)(hb1 + 16 * kt);
    }
    f32x4 accP[4];
    #pragma unroll
    for (int j = 0; j < 4; ++j) accP[j] = bias[j];
    #pragma unroll
    for (int kt = 0; kt < 4; ++kt)
      #pragma unroll
      for (int j = 0; j < 4; ++j) {
        accP[j] = mfma16(aW[j][kt], b0r[kt], accP[j]);
        accP[j] = mfma16(aV[j][kt], b1r[kt], accP[j]);
      }
    float hvv[4];
    creg0 = sigf(accP[1][0]) * creg0 + sigf(accP[0][0]) * tanh_fast(accP[2][0]);
    hvv[0] = sigf(accP[3][0]) * tanh_fast(creg0);
    creg1 = sigf(accP[1][1]) * creg1 + sigf(accP[0][1]) * tanh_fast(accP[2][1]);
    hvv[1] = sigf(accP[3][1]) * tanh_fast(creg1);
    creg2 = sigf(accP[1][2]) * creg2 + sigf(accP[0][2]) * tanh_fast(accP[2][2]);
    hvv[2] = sigf(accP[3][2]) * tanh_fast(creg2);
    creg3 = sigf(accP[1][3]) * creg3 + sigf(accP[0][3]) * tanh_fast(accP[2][3]);
    hvv[3] = sigf(accP[3][3]) * tanh_fast(creg3);
    f32x4 st = {hvv[0], hvv[1], hvv[2], hvv[3]};
    *(f32x4*)&hf[n][e0] = st;
  }
  __syncthreads();

  // classifier: wave w handles batch cols 2w, 2w+1; lane l = hidden row j
  {
    float4 w1r[16];
    #pragma unroll
    for (int c = 0; c < 16; ++c) w1r[c] = *(const float4*)(W1 + l * HID + 4 * c);
    float w2v = W2[l];
    float cb = clsb1[l];
    float b2v = clsb2[0];
    #pragma unroll
    for (int s = 0; s < 2; ++s) {
      int nn = 2 * w + s;
      float z0 = cb, z1 = 0.f, z2 = 0.f, z3 = 0.f;
      #pragma unroll
      for (int c = 0; c < 16; ++c) {
        float4 wv = w1r[c];
        const float* hp = &hf[nn][4 * c];
        z0 = fmaf(hp[0], wv.x, z0);
        z1 = fmaf(hp[1], wv.y, z1);
        z2 = fmaf(hp[2], wv.z, z2);
        z3 = fmaf(hp[3], wv.w, z3);
      }
      float z = fmaxf((z0 + z1) + (z2 + z3), 0.f);
      float v = z * w2v;
      v += __shfl_xor(v, 1);
      v += __shfl_xor(v, 2);
      v += __shfl_xor(v, 4);
      v += __shfl_xor(v, 8);
      v += __shfl_xor(v, 16);
      v += __shfl_xor(v, 32);
      if (l == 0) out[blockIdx.x * NB + nn] = sigf(v + b2v);
    }
  }
}

extern "C" void kernel_launch(void* const* d_in, const int* in_sizes, int n_in,
                              void* d_out, int out_size, void* d_ws, size_t ws_size,
                              hipStream_t stream) {
  const int*   x    = (const int*)d_in[0];
  const float* emb  = (const float*)d_in[1];
  const float* Wih0 = (const float*)d_in[2];
  const float* Whh0 = (const float*)d_in[3];
  const float* bih0 = (const float*)d_in[4];
  const float* bhh0 = (const float*)d_in[5];
  const float* Wih1 = (const float*)d_in[6];
  const float* Whh1 = (const float*)d_in[7];
  const float* bih1 = (const float*)d_in[8];
  const float* bhh1 = (const float*)d_in[9];
  const float* W1   = (const float*)d_in[10];
  const float* b1   = (const float*)d_in[11];
  const float* W2   = (const float*)d_in[12];
  const float* b2   = (const float*)d_in[13];
  float* out = (float*)d_out;

  char* ws = (char*)d_ws;
  u16* xwT = (u16*)ws;                      ws += (size_t)NBLK * SEQ * TILE * sizeof(u16); // 64MB
  u32* Wih0h = (u32*)ws;                    ws += (size_t)G4 * WPK * sizeof(u32);
  u32* Whh0h = (u32*)ws;                    ws += (size_t)G4 * 32 * sizeof(u32);
  u32* Wih1h = (u32*)ws;                    ws += (size_t)G4 * 32 * sizeof(u32);
  u32* Whh1h = (u32*)ws;                    ws += (size_t)G4 * 32 * sizeof(u32);
  float* b0c = (float*)ws;                  ws += G4 * sizeof(float);
  float* b1c = (float*)ws;                  ws += G4 * sizeof(float);

  prep_kernel<<<1, 256, 0, stream>>>(Wih0, Whh0, Wih1, Whh1, bih0, bhh0, bih1, bhh1,
                                     Wih0h, b0c, b1c, Whh0h, Wih1h, Whh1h);
  xw0_kernel<<<(NBLK) * (SEQ / TCHK), 256, 0, stream>>>(x, emb, Wih0h, b0c, xwT);
  lstm_fused_kernel<<<NBLK, 512, 0, stream>>>(xwT, Whh0h, Wih1h, Whh1h, b1c,
                                              W1, b1, W2, b2, out);
}

// Round 8
// 1038.871 us; speedup vs baseline: 2.0895x; 2.0895x over previous
//
#include <hip/hip_runtime.h>
#include <hip/hip_bf16.h>

#define EMB_D 100
#define HID 64
#define G4 256
#define BATCH 128
#define SEQ 1024
#define TOK 16

typedef _Float16 half2v __attribute__((ext_vector_type(2)));

__device__ __forceinline__ float sigf(float x) { return 1.0f / (1.0f + __expf(-x)); }
__device__ __forceinline__ float tanh_fast(float x) {
  float t = __expf(-2.0f * fabsf(x));
  float r = (1.0f - t) / (1.0f + t);
  return copysignf(r, x);
}

__device__ __forceinline__ float dot2(unsigned int h, unsigned int w, float acc) {
  return __builtin_amdgcn_fdot2(__builtin_bit_cast(half2v, h),
                                __builtin_bit_cast(half2v, w), acc, false);
}

__device__ __forceinline__ unsigned int packh2(float lo, float hi) {
  unsigned short a = __builtin_bit_cast(unsigned short, (_Float16)lo);
  unsigned short b = __builtin_bit_cast(unsigned short, (_Float16)hi);
  return (unsigned int)a | ((unsigned int)b << 16);
}

// DPP quad_perm lane swaps within each 4-lane group: single VALU instr,
// replaces LDS-latency __shfl_xor on the activation critical path.
#define QP_XOR1 0xB1  // perm [1,0,3,2]
#define QP_XOR2 0x4E  // perm [2,3,0,1]
#define QP_XOR3 0x1B  // perm [3,2,1,0]
#define QPERM(x, ctrl)                                                        \
  __builtin_bit_cast(float, __builtin_amdgcn_mov_dpp(                         \
      __builtin_bit_cast(int, (x)), (ctrl), 0xF, 0xF, true))

// --- prep: combined biases, transposed Wih0, f16-packed recurrent weights ---
__global__ void prep_kernel(const float* __restrict__ Wih0,
                            const float* __restrict__ Whh0, const float* __restrict__ Wih1,
                            const float* __restrict__ Whh1,
                            const float* __restrict__ bih0, const float* __restrict__ bhh0,
                            const float* __restrict__ bih1, const float* __restrict__ bhh1,
                            float* __restrict__ Wih0T, float* __restrict__ b0c,
                            float* __restrict__ b1c,
                            unsigned int* __restrict__ Whh0h,
                            unsigned int* __restrict__ Wih1h,
                            unsigned int* __restrict__ Whh1h) {
  int g = threadIdx.x;   // 0..255 = gate row
  b0c[g] = bih0[g] + bhh0[g];
  b1c[g] = bih1[g] + bhh1[g];
  for (int d = 0; d < EMB_D; ++d) Wih0T[d * G4 + g] = Wih0[g * EMB_D + d];
  for (int d = 0; d < HID / 2; ++d) {
    Whh0h[g * 32 + d] = packh2(Whh0[g * HID + 2 * d], Whh0[g * HID + 2 * d + 1]);
    Wih1h[g * 32 + d] = packh2(Wih1[g * HID + 2 * d], Wih1[g * HID + 2 * d + 1]);
    Whh1h[g * 32 + d] = packh2(Whh1[g * HID + 2 * d], Whh1[g * HID + 2 * d + 1]);
  }
}

// --- xw0[token][gate] = emb[x[token]] . Wih0[gate] + b0, stored f16 ---
__global__ __attribute__((amdgpu_waves_per_eu(1, 4))) __launch_bounds__(256)
void xw0_kernel(
    const int* __restrict__ x, const float* __restrict__ emb,
    const float* __restrict__ Wih0T, const float* __restrict__ b0c,
    _Float16* __restrict__ xw0h) {
  __shared__ int sidx[TOK];
  __shared__ float erow[TOK][EMB_D];
  int g = threadIdx.x;
  long t0 = (long)blockIdx.x * TOK;

  if (g < TOK) sidx[g] = x[t0 + g];
  __syncthreads();
  for (int i = g; i < TOK * EMB_D; i += 256) {
    int tok = i / EMB_D;
    int d = i - tok * EMB_D;
    erow[tok][d] = emb[(long)sidx[tok] * EMB_D + d];
  }

  float w[EMB_D];
  #pragma unroll
  for (int d = 0; d < EMB_D; ++d) w[d] = Wih0T[d * G4 + g];
  float bb = b0c[g];
  __syncthreads();

  for (int tok = 0; tok < TOK; ++tok) {
    const float* ev = erow[tok];
    float a0 = bb, a1 = 0.f, a2 = 0.f, a3 = 0.f;
    #pragma unroll
    for (int d = 0; d < EMB_D; d += 4) {
      a0 = fmaf(w[d],     ev[d],     a0);
      a1 = fmaf(w[d + 1], ev[d + 1], a1);
      a2 = fmaf(w[d + 2], ev[d + 2], a2);
      a3 = fmaf(w[d + 3], ev[d + 3], a3);
    }
    xw0h[(t0 + tok) * G4 + g] = (_Float16)((a0 + a1) + (a2 + a3));
  }
}

// --- fused 2-layer recurrence, in-wave gate quartets ---
// 128 blocks (1 row), 512 threads = 8 waves. Waves 0-3: layer0, waves 4-7:
// layer1. Lane 4m+k of wave w computes the FULL dot for gate k of element
// e = 16*eg + m. Quartet (i,f,g,o) gathered via DPP quad_perm (VALU, no LDS).
// Per-step sync: s_waitcnt lgkmcnt(0) + raw s_barrier ONLY — the distance-2
// global xw prefetch rides across the barrier (no vmcnt(0) drain per step).
__global__ __launch_bounds__(512, 2) void lstm_fused_kernel(
    const _Float16* __restrict__ xw0h,
    const unsigned int* __restrict__ Whh0h, const unsigned int* __restrict__ Wih1h,
    const unsigned int* __restrict__ Whh1h, const float* __restrict__ b1c,
    const float* __restrict__ W1, const float* __restrict__ clsb1,
    const float* __restrict__ W2, const float* __restrict__ clsb2,
    float* __restrict__ out) {
  int tid = threadIdx.x;
  int lane = tid & 63;
  int w = tid >> 6;
  bool isL1 = (w >= 4);
  int eg = isL1 ? (w - 4) : w;
  int e = eg * 16 + (lane >> 2);
  int k = lane & 3;
  int row = k * HID + e;          // gate row in [0,256)
  int b = blockIdx.x;

  __shared__ alignas(16) _Float16 h0s[2][HID];
  __shared__ alignas(16) _Float16 h1s[2][HID];
  __shared__ alignas(16) float hf[HID];

  // per-lane weight rows, f16-packed: L0 = Whh0 row; L1 = Wih1 + Whh1 rows
  uint4 wA[8], wB[8];
  if (!isL1) {
    const uint4* p = (const uint4*)(Whh0h + row * 32);
    #pragma unroll
    for (int c = 0; c < 8; ++c) wA[c] = p[c];
  } else {
    const uint4* p = (const uint4*)(Wih1h + row * 32);
    const uint4* q = (const uint4*)(Whh1h + row * 32);
    #pragma unroll
    for (int c = 0; c < 8; ++c) { wA[c] = p[c]; wB[c] = q[c]; }
  }
  float bias = isL1 ? b1c[row] : 0.f;

  if (tid < 2 * HID) {
    int j = tid & (HID - 1);
    if (tid < HID) { h0s[0][j] = (_Float16)0.f; h0s[1][j] = (_Float16)0.f; }
    else           { h1s[0][j] = (_Float16)0.f; h1s[1][j] = (_Float16)0.f; }
  }

  const _Float16* xr = xw0h + (long)b * SEQ * G4 + row;
  float xw_t = 0.f, xw_t1 = 0.f;
  if (!isL1) { xw_t = (float)xr[0]; xw_t1 = (float)xr[G4]; }
  float c_reg = 0.f;
  __syncthreads();   // prologue: h buffers + prologue loads visible

  for (int t = 0; t < SEQ; ++t) {
    float xw_t2 = 0.f;
    if (!isL1) {
      int tn = (t + 2 < SEQ) ? (t + 2) : (SEQ - 1);
      xw_t2 = (float)xr[(long)tn * G4];
    }
    int rb = (t + 1) & 1, wbuf = t & 1;
    const uint4* h0p = (const uint4*)h0s[rb];
    float a0, a1 = 0.f, a2 = 0.f, a3 = 0.f;
    if (!isL1) {
      a0 = xw_t;
      #pragma unroll
      for (int c = 0; c < 8; ++c) {
        uint4 h = h0p[c];
        a0 = dot2(h.x, wA[c].x, a0);
        a1 = dot2(h.y, wA[c].y, a1);
        a2 = dot2(h.z, wA[c].z, a2);
        a3 = dot2(h.w, wA[c].w, a3);
      }
    } else {
      const uint4* h1p = (const uint4*)h1s[rb];
      a0 = bias;
      #pragma unroll
      for (int c = 0; c < 8; ++c) {
        uint4 h = h0p[c];
        a0 = dot2(h.x, wA[c].x, a0);
        a1 = dot2(h.y, wA[c].y, a1);
        a2 = dot2(h.z, wA[c].z, a2);
        a3 = dot2(h.w, wA[c].w, a3);
      }
      #pragma unroll
      for (int c = 0; c < 8; ++c) {
        uint4 h = h1p[c];
        a0 = dot2(h.x, wB[c].x, a0);
        a1 = dot2(h.y, wB[c].y, a1);
        a2 = dot2(h.z, wB[c].z, a2);
        a3 = dot2(h.w, wB[c].w, a3);
      }
    }
    float gown = (a0 + a1) + (a2 + a3);
    float gx1 = QPERM(gown, QP_XOR1);
    float gx2 = QPERM(gown, QP_XOR2);
    float gx3 = QPERM(gown, QP_XOR3);
    // valid in lanes with k==0: i=gown, f=gx1, g=gx2, o=gx3
    bool act = (!isL1) || (t > 0);
    if (act) {
      c_reg = sigf(gx1) * c_reg + sigf(gown) * tanh_fast(gx2);
      float hv = sigf(gx3) * tanh_fast(c_reg);
      if (k == 0) {
        _Float16 h16 = (_Float16)hv;
        if (isL1) h1s[wbuf][e] = h16; else h0s[wbuf][e] = h16;
      }
    }
    xw_t = xw_t1; xw_t1 = xw_t2;
    // drain LDS writes only; global prefetch stays in flight across barrier
    asm volatile("s_waitcnt lgkmcnt(0)" ::: "memory");
    __builtin_amdgcn_s_barrier();
    asm volatile("" ::: "memory");
  }

  // extra layer-1 step: h1[1023] from h0[1023], h1[1022] (both in buf 1)
  if (isL1) {
    const uint4* h0p = (const uint4*)h0s[1];
    const uint4* h1p = (const uint4*)h1s[1];
    float a0 = bias, a1 = 0.f, a2 = 0.f, a3 = 0.f;
    #pragma unroll
    for (int c = 0; c < 8; ++c) {
      uint4 h = h0p[c];
      a0 = dot2(h.x, wA[c].x, a0);
      a1 = dot2(h.y, wA[c].y, a1);
      a2 = dot2(h.z, wA[c].z, a2);
      a3 = dot2(h.w, wA[c].w, a3);
    }
    #pragma unroll
    for (int c = 0; c < 8; ++c) {
      uint4 h = h1p[c];
      a0 = dot2(h.x, wB[c].x, a0);
      a1 = dot2(h.y, wB[c].y, a1);
      a2 = dot2(h.z, wB[c].z, a2);
      a3 = dot2(h.w, wB[c].w, a3);
    }
    float gown = (a0 + a1) + (a2 + a3);
    float gx1 = QPERM(gown, QP_XOR1);
    float gx2 = QPERM(gown, QP_XOR2);
    float gx3 = QPERM(gown, QP_XOR3);
    c_reg = sigf(gx1) * c_reg + sigf(gown) * tanh_fast(gx2);
    float hv = sigf(gx3) * tanh_fast(c_reg);
    if (k == 0) hf[e] = hv;
  }
  __syncthreads();

  // classifier (wave 0): z = relu(h1.W1^T + b1); out = sigmoid(z.W2 + b2)
  if (w == 0) {
    int j = lane;
    const float4* wp = (const float4*)(W1 + j * HID);
    const float4* hp = (const float4*)hf;
    float z0 = clsb1[j], z1 = 0.f, z2 = 0.f, z3 = 0.f;
    #pragma unroll
    for (int c = 0; c < 16; ++c) {
      float4 wv = wp[c];
      float4 hv = hp[c];
      z0 = fmaf(hv.x, wv.x, z0);
      z1 = fmaf(hv.y, wv.y, z1);
      z2 = fmaf(hv.z, wv.z, z2);
      z3 = fmaf(hv.w, wv.w, z3);
    }
    float z = fmaxf((z0 + z1) + (z2 + z3), 0.f);
    float v = z * W2[j];
    v += __shfl_xor(v, 1);
    v += __shfl_xor(v, 2);
    v += __shfl_xor(v, 4);
    v += __shfl_xor(v, 8);
    v += __shfl_xor(v, 16);
    v += __shfl_xor(v, 32);
    if (lane == 0) out[b] = sigf(v + clsb2[0]);
  }
}

extern "C" void kernel_launch(void* const* d_in, const int* in_sizes, int n_in,
                              void* d_out, int out_size, void* d_ws, size_t ws_size,
                              hipStream_t stream) {
  const int*   x    = (const int*)d_in[0];
  const float* emb  = (const float*)d_in[1];
  const float* Wih0 = (const float*)d_in[2];
  const float* Whh0 = (const float*)d_in[3];
  const float* bih0 = (const float*)d_in[4];
  const float* bhh0 = (const float*)d_in[5];
  const float* Wih1 = (const float*)d_in[6];
  const float* Whh1 = (const float*)d_in[7];
  const float* bih1 = (const float*)d_in[8];
  const float* bhh1 = (const float*)d_in[9];
  const float* W1   = (const float*)d_in[10];
  const float* b1   = (const float*)d_in[11];
  const float* W2   = (const float*)d_in[12];
  const float* b2   = (const float*)d_in[13];
  float* out = (float*)d_out;

  char* ws = (char*)d_ws;
  const size_t XW0_BYTES = (size_t)BATCH * SEQ * G4 * sizeof(_Float16);  // 67108864
  _Float16* xw0h = (_Float16*)ws;                 ws += XW0_BYTES;
  float* Wih0T   = (float*)ws;                    ws += (size_t)EMB_D * G4 * sizeof(float);
  float* b0c     = (float*)ws;                    ws += G4 * sizeof(float);
  float* b1c     = (float*)ws;                    ws += G4 * sizeof(float);
  unsigned int* Whh0h = (unsigned int*)ws;        ws += (size_t)G4 * 32 * sizeof(unsigned int);
  unsigned int* Wih1h = (unsigned int*)ws;        ws += (size_t)G4 * 32 * sizeof(unsigned int);
  unsigned int* Whh1h = (unsigned int*)ws;        ws += (size_t)G4 * 32 * sizeof(unsigned int);

  prep_kernel<<<1, 256, 0, stream>>>(Wih0, Whh0, Wih1, Whh1, bih0, bhh0, bih1, bhh1,
                                     Wih0T, b0c, b1c, Whh0h, Wih1h, Whh1h);
  xw0_kernel<<<(BATCH * SEQ) / TOK, 256, 0, stream>>>(x, emb, Wih0T, b0c, xw0h);
  lstm_fused_kernel<<<BATCH, 512, 0, stream>>>(xw0h, Whh0h, Wih1h, Whh1h, b1c,
                                               W1, b1, W2, b2, out);
}